// Round 3
// baseline (797.903 us; speedup 1.0000x reference)
//
#include <hip/hip_runtime.h>
#include <math.h>

typedef unsigned short u16;
typedef unsigned int u32;
typedef __bf16 bf16x8 __attribute__((ext_vector_type(8)));
typedef float f32x4 __attribute__((ext_vector_type(4)));

// ---- problem constants ----
#define BB 4
#define CC 384
#define HH 56
#define WW 56
#define GG 12
#define GCC 32
#define KK 9
#define HWD 3136           // H*W
#define NT 12544           // B*H*W tokens
#define HID 1536
#define EPSV 1e-5f

__device__ __forceinline__ float b2f(u16 u) {
  union { float f; u32 u; } c; c.u = ((u32)u) << 16; return c.f;
}
__device__ __forceinline__ u16 f2b(float f) {
  union { float f; u32 u; } c; c.f = f;
  u32 r = c.u + 0x7FFFu + ((c.u >> 16) & 1u);
  return (u16)(r >> 16);
}

// =====================================================================
// Probe: ln1_g[0] == 1.0f exactly. f32 -> first u32 is 0x3F800000;
// bf16 pair (1.0,1.0) -> 0x3F803F80. flag=1 means f32 inputs.
// =====================================================================
__global__ void probe_kernel(const void* __restrict__ g, int* __restrict__ flag) {
  if (threadIdx.x == 0 && blockIdx.x == 0) {
    u32 u = *(const u32*)g;
    *flag = (u == 0x3F800000u) ? 1 : 0;
  }
}

// =====================================================================
// Convert an external vector (bf16 or f32 per flag) to canonical f32.
// =====================================================================
__global__ void convert_vec(const void* __restrict__ in, float* __restrict__ out,
                            int n, const int* __restrict__ flag) {
  int i = blockIdx.x * 256 + threadIdx.x;
  if (i >= n) return;
  if (*flag) out[i] = ((const float*)in)[i];
  else out[i] = b2f(((const u16*)in)[i]);
}

// =====================================================================
// Convert + transpose weight: in (K x N, bf16|f32) -> out (N x K) bf16
// =====================================================================
__global__ void convert_wT(const void* __restrict__ in, u16* __restrict__ out,
                           int K, int N, const int* __restrict__ flag) {
  int idx = blockIdx.x * 256 + threadIdx.x;
  int kq = K >> 2;
  if (idx >= N * kq) return;
  int n = idx / kq;
  int k4 = (idx - n * kq) << 2;
  u16 e[4];
  if (*flag) {
    const float* f = (const float*)in;
#pragma unroll
    for (int r = 0; r < 4; r++) e[r] = f2b(f[(size_t)(k4 + r) * N + n]);
  } else {
    const u16* hh = (const u16*)in;
#pragma unroll
    for (int r = 0; r < 4; r++) e[r] = hh[(size_t)(k4 + r) * N + n];
  }
  uint2 pk;
  pk.x = (u32)e[0] | ((u32)e[1] << 16);
  pk.y = (u32)e[2] | ((u32)e[3] << 16);
  *reinterpret_cast<uint2*>(&out[(size_t)n * K + k4]) = pk;
}

// =====================================================================
// LN1 + NCHW->NHWC transpose. x: (B,C,HW) (bf16|f32) -> tn: (NT,C) bf16
// One block handles 64 tokens (hw) of one batch b.
// =====================================================================
__global__ __launch_bounds__(256) void ln1_kernel(
    const void* __restrict__ x, const float* __restrict__ gam,
    const float* __restrict__ bet, u16* __restrict__ tn,
    const int* __restrict__ flag) {
  __shared__ u16 tile[64 * 385];
  const int t = threadIdx.x;
  const int blk = blockIdx.x;
  const int b = blk / 49;
  const int hw0 = (blk - b * 49) * 64;
  const int dtf = *flag;

  const int cofs = t >> 3;        // 0..31
  const int hofs = (t & 7) * 8;   // 0..56
  if (dtf) {
    const float* xf = (const float*)x;
#pragma unroll
    for (int it = 0; it < 12; it++) {
      int cc = it * 32 + cofs;
      size_t base = ((size_t)b * CC + cc) * HWD + hw0 + hofs;
      float4 a0 = *reinterpret_cast<const float4*>(&xf[base]);
      float4 a1 = *reinterpret_cast<const float4*>(&xf[base + 4]);
      tile[(hofs + 0) * 385 + cc] = f2b(a0.x);
      tile[(hofs + 1) * 385 + cc] = f2b(a0.y);
      tile[(hofs + 2) * 385 + cc] = f2b(a0.z);
      tile[(hofs + 3) * 385 + cc] = f2b(a0.w);
      tile[(hofs + 4) * 385 + cc] = f2b(a1.x);
      tile[(hofs + 5) * 385 + cc] = f2b(a1.y);
      tile[(hofs + 6) * 385 + cc] = f2b(a1.z);
      tile[(hofs + 7) * 385 + cc] = f2b(a1.w);
    }
  } else {
    const u16* xh = (const u16*)x;
#pragma unroll
    for (int it = 0; it < 12; it++) {
      int cc = it * 32 + cofs;
      uint4 v = *reinterpret_cast<const uint4*>(
          &xh[((size_t)b * CC + cc) * HWD + hw0 + hofs]);
      u32 uu[4] = {v.x, v.y, v.z, v.w};
#pragma unroll
      for (int r = 0; r < 4; r++) {
        tile[(hofs + 2 * r + 0) * 385 + cc] = (u16)(uu[r] & 0xFFFFu);
        tile[(hofs + 2 * r + 1) * 385 + cc] = (u16)(uu[r] >> 16);
      }
    }
  }
  __syncthreads();

  const int lane = t & 63;
  const int wv = t >> 6;
  for (int tk = wv; tk < 64; tk += 4) {
    float v[6];
    float s = 0.f;
#pragma unroll
    for (int j = 0; j < 6; j++) {
      v[j] = b2f(tile[tk * 385 + j * 64 + lane]);
      s += v[j];
    }
#pragma unroll
    for (int off = 32; off > 0; off >>= 1) s += __shfl_xor(s, off);
    float mu = s * (1.f / 384.f);
    float q = 0.f;
#pragma unroll
    for (int j = 0; j < 6; j++) {
      float d = v[j] - mu;
      q += d * d;
    }
#pragma unroll
    for (int off = 32; off > 0; off >>= 1) q += __shfl_xor(q, off);
    float rs = rsqrtf(q * (1.f / 384.f) + EPSV);
    size_t row = ((size_t)b * HWD + hw0 + tk) * CC;
#pragma unroll
    for (int j = 0; j < 6; j++) {
      int cc = j * 64 + lane;
      float y = (v[j] - mu) * rs * gam[cc] + bet[cc];
      tn[row + cc] = f2b(y);
    }
  }
}

// =====================================================================
// LN2: xp1 (NT,C) bf16 -> y2 (NT,C) bf16. One wave per token.
// =====================================================================
__global__ __launch_bounds__(256) void ln2_kernel(
    const u16* __restrict__ xp1, const float* __restrict__ gam,
    const float* __restrict__ bet, u16* __restrict__ y2) {
  const int tok = blockIdx.x * 4 + (threadIdx.x >> 6);
  const int lane = threadIdx.x & 63;
  const u16* row = xp1 + (size_t)tok * CC;
  float v[6];
  float s = 0.f;
#pragma unroll
  for (int j = 0; j < 6; j++) {
    v[j] = b2f(row[j * 64 + lane]);
    s += v[j];
  }
#pragma unroll
  for (int off = 32; off > 0; off >>= 1) s += __shfl_xor(s, off);
  float mu = s * (1.f / 384.f);
  float q = 0.f;
#pragma unroll
  for (int j = 0; j < 6; j++) {
    float d = v[j] - mu;
    q += d * d;
  }
#pragma unroll
  for (int off = 32; off > 0; off >>= 1) q += __shfl_xor(q, off);
  float rs = rsqrtf(q * (1.f / 384.f) + EPSV);
#pragma unroll
  for (int j = 0; j < 6; j++) {
    int cc = j * 64 + lane;
    y2[(size_t)tok * CC + cc] = f2b((v[j] - mu) * rs * gam[cc] + bet[cc]);
  }
}

// =====================================================================
// DCNv4 sampling. val (NT, C) bf16 [c = g*32+gc], om (NT,324) f32,
// dcn out (NT, C) bf16. 32 lanes = 32 channels of one (b,hw,g).
// =====================================================================
__global__ __launch_bounds__(256) void dcn_kernel(
    const u16* __restrict__ val, const float* __restrict__ om,
    u16* __restrict__ dcn) {
  const int u = blockIdx.x * 8 + (threadIdx.x >> 5);
  const int c = threadIdx.x & 31;
  const int g = u % GG;
  const int bhw = u / GG;
  const int hw = bhw % HWD;
  const int b = bhw / HWD;
  const int wx = hw % WW;
  const int hy = hw / WW;
  const float* o = om + (size_t)bhw * 324 + g * 27;
  const u16* vb = val + (size_t)b * HWD * CC + g * GCC + c;
  float acc = 0.f;
#pragma unroll
  for (int k = 0; k < KK; k++) {
    float dx = o[2 * k];
    float dy = o[2 * k + 1];
    float mw = o[18 + k];
    float px = (float)(wx + (k % 3) - 1) + dx;
    float py = (float)(hy + (k / 3) - 1) + dy;
    float x0f = floorf(px), y0f = floorf(py);
    float tx = px - x0f, ty = py - y0f;
    int x0 = (int)x0f, y0 = (int)y0f;
    int x1 = x0 + 1, y1 = y0 + 1;
    bool xv0 = (x0 >= 0) && (x0 < WW);
    bool xv1 = (x1 >= 0) && (x1 < WW);
    bool yv0 = (y0 >= 0) && (y0 < HH);
    bool yv1 = (y1 >= 0) && (y1 < HH);
    float v00 = (yv0 && xv0) ? b2f(vb[(size_t)(y0 * WW + x0) * CC]) : 0.f;
    float v01 = (yv0 && xv1) ? b2f(vb[(size_t)(y0 * WW + x1) * CC]) : 0.f;
    float v10 = (yv1 && xv0) ? b2f(vb[(size_t)(y1 * WW + x0) * CC]) : 0.f;
    float v11 = (yv1 && xv1) ? b2f(vb[(size_t)(y1 * WW + x1) * CC]) : 0.f;
    float top = v00 * (1.f - tx) + v01 * tx;
    float bot = v10 * (1.f - tx) + v11 * tx;
    acc += mw * (top * (1.f - ty) + bot * ty);
  }
  dcn[(size_t)bhw * CC + g * GCC + c] = f2b(acc);
}

// =====================================================================
// GEMM: out(M,N) = A(M,K) @ W(K,N) + bias(f32), Wt (N,K) bf16.
// 128x128 tile, 4 waves of 64x64, BK=32, mfma_f32_16x16x32_bf16.
// MODE 0: bf16 out (row-major M x N), N-guarded.
// MODE 1: f32 out, N-guarded.
// MODE 2: bf16 out + residual from external x in NCHW (dtype per flag).
// MODE 3: external out (NCHW, dtype per flag) + bf16 residual (xp1); moff.
// =====================================================================
template <int MODE, bool GELU>
__global__ __launch_bounds__(256) void gemm_k(
    const u16* __restrict__ A, const u16* __restrict__ Wt,
    const float* __restrict__ bias, const void* __restrict__ res,
    void* __restrict__ out, int M, int N, int K, int moff,
    const int* __restrict__ flag) {
  __shared__ u16 As[128 * 40];
  __shared__ u16 Bs[128 * 40];
  const int t = threadIdx.x;
  const int m0 = blockIdx.x * 128;
  const int n0 = blockIdx.y * 128;
  const int sr = t >> 3;          // 0..31
  const int sc = (t & 7) << 2;    // 0..28
  const int lane = t & 63;
  const int wv = t >> 6;
  const int wm = (wv >> 1) << 6;
  const int wn = (wv & 1) << 6;
  const int fr = lane & 15;
  const int quad = lane >> 4;
  const int dtf = (MODE >= 2) ? *flag : 0;

  f32x4 acc[4][4];
#pragma unroll
  for (int mi = 0; mi < 4; mi++)
#pragma unroll
    for (int ni = 0; ni < 4; ni++) acc[mi][ni] = f32x4{0.f, 0.f, 0.f, 0.f};

  for (int kb = 0; kb < K; kb += 32) {
    __syncthreads();
#pragma unroll
    for (int i = 0; i < 4; i++) {
      int r = (i << 5) + sr;
      *reinterpret_cast<uint2*>(&As[r * 40 + sc]) =
          *reinterpret_cast<const uint2*>(&A[(size_t)(m0 + r) * K + kb + sc]);
    }
#pragma unroll
    for (int i = 0; i < 4; i++) {
      int r = (i << 5) + sr;
      uint2 v = make_uint2(0u, 0u);
      if (n0 + r < N)
        v = *reinterpret_cast<const uint2*>(&Wt[(size_t)(n0 + r) * K + kb + sc]);
      *reinterpret_cast<uint2*>(&Bs[r * 40 + sc]) = v;
    }
    __syncthreads();
    bf16x8 av[4], bv[4];
#pragma unroll
    for (int mi = 0; mi < 4; mi++)
      av[mi] = *reinterpret_cast<const bf16x8*>(
          &As[(wm + mi * 16 + fr) * 40 + quad * 8]);
#pragma unroll
    for (int ni = 0; ni < 4; ni++)
      bv[ni] = *reinterpret_cast<const bf16x8*>(
          &Bs[(wn + ni * 16 + fr) * 40 + quad * 8]);
#pragma unroll
    for (int mi = 0; mi < 4; mi++)
#pragma unroll
      for (int ni = 0; ni < 4; ni++)
        acc[mi][ni] = __builtin_amdgcn_mfma_f32_16x16x32_bf16(
            av[mi], bv[ni], acc[mi][ni], 0, 0, 0);
  }

  // epilogue
  float bias_v[4];
#pragma unroll
  for (int ni = 0; ni < 4; ni++) {
    int n = n0 + wn + ni * 16 + fr;
    bias_v[ni] = (n < N) ? bias[n] : 0.f;
  }
#pragma unroll
  for (int mi = 0; mi < 4; mi++) {
#pragma unroll
    for (int ni = 0; ni < 4; ni++) {
      int n = n0 + wn + ni * 16 + fr;
      int mbase = m0 + wm + mi * 16 + quad * 4;
      if (MODE == 3) {
        // out external NCHW (dtype per flag), residual bf16 xp1
        const u16* rf = (const u16*)res;
        int mg = mbase + moff;
        int b = mg / HWD;
        int hw = mg - b * HWD;
        float vv[4];
#pragma unroll
        for (int r = 0; r < 4; r++)
          vv[r] = acc[mi][ni][r] + bias_v[ni] + b2f(rf[(size_t)(mg + r) * CC + n]);
        if (dtf) {
          float4 st = make_float4(vv[0], vv[1], vv[2], vv[3]);
          *reinterpret_cast<float4*>(
              &((float*)out)[((size_t)b * CC + n) * HWD + hw]) = st;
        } else {
          uint2 st;
          st.x = (u32)f2b(vv[0]) | ((u32)f2b(vv[1]) << 16);
          st.y = (u32)f2b(vv[2]) | ((u32)f2b(vv[3]) << 16);
          *reinterpret_cast<uint2*>(
              &((u16*)out)[((size_t)b * CC + n) * HWD + hw]) = st;
        }
      } else if (MODE == 2) {
        // residual read from external NCHW x (dtype per flag), bf16 out
        int b = mbase / HWD;
        int hw = mbase - b * HWD;
        float rv[4];
        if (dtf) {
          const float* xf = (const float*)res;
          float4 q = *reinterpret_cast<const float4*>(
              &xf[((size_t)b * CC + n) * HWD + hw]);
          rv[0] = q.x; rv[1] = q.y; rv[2] = q.z; rv[3] = q.w;
        } else {
          const u16* xh = (const u16*)res;
          uint2 q = *reinterpret_cast<const uint2*>(
              &xh[((size_t)b * CC + n) * HWD + hw]);
          rv[0] = b2f((u16)(q.x & 0xFFFFu));
          rv[1] = b2f((u16)(q.x >> 16));
          rv[2] = b2f((u16)(q.y & 0xFFFFu));
          rv[3] = b2f((u16)(q.y >> 16));
        }
#pragma unroll
        for (int r = 0; r < 4; r++) {
          float vv = acc[mi][ni][r] + bias_v[ni] + rv[r];
          ((u16*)out)[(size_t)(mbase + r) * CC + n] = f2b(vv);
        }
      } else {
#pragma unroll
        for (int r = 0; r < 4; r++) {
          int m = mbase + r;
          float vv = acc[mi][ni][r] + bias_v[ni];
          if (GELU) vv = 0.5f * vv * (1.0f + erff(vv * 0.70710678118654752f));
          if (MODE == 0) {
            if (n < N) ((u16*)out)[(size_t)m * N + n] = f2b(vv);
          } else if (MODE == 1) {
            if (n < N) ((float*)out)[(size_t)m * N + n] = vv;
          }
        }
      }
    }
  }
}

// =====================================================================
extern "C" void kernel_launch(void* const* d_in, const int* in_sizes, int n_in,
                              void* d_out, int out_size, void* d_ws,
                              size_t ws_size, hipStream_t stream) {
  const void* x = d_in[0];
  const void* ln1_g = d_in[1];
  const void* ln1_b = d_in[2];
  const void* vproj_w = d_in[3];
  const void* vproj_b = d_in[4];
  const void* om_w = d_in[5];
  const void* om_b = d_in[6];
  const void* oproj_w = d_in[7];
  const void* oproj_b = d_in[8];
  const void* ln2_g = d_in[9];
  const void* ln2_b = d_in[10];
  const void* fc1_w = d_in[11];
  const void* fc1_b = d_in[12];
  const void* fc2_w = d_in[13];
  const void* fc2_b = d_in[14];

  char* ws = (char*)d_ws;
  const size_t SZ_NC2 = (size_t)NT * CC * 2;         // 9,633,792
  const size_t SZ_H1 = (size_t)3200 * HID * 2;       // 9,830,400 (max h chunk)
  const size_t SZ_OM4 = (size_t)NT * 324 * 4;        // 16,257,024
  // R0: tn -> dcn -> y2
  u16* tn = (u16*)(ws);
  u16* dcn = tn;
  u16* y2 = tn;
  // R1: val -> h (chunked)
  u16* val = (u16*)(ws + SZ_NC2);
  u16* h = val;
  // R2: om f32
  float* om = (float*)(ws + SZ_NC2 + SZ_H1);
  // R3: xp1 bf16
  u16* xp1 = (u16*)(ws + SZ_NC2 + SZ_H1 + SZ_OM4);
  // R4: transposed weights bf16
  u16* wT = (u16*)(ws + 2 * SZ_NC2 + SZ_H1 + SZ_OM4);
  u16* vprojT = wT;                       // 384x384
  u16* omT = vprojT + 384 * 384;          // 324x384
  u16* oprojT = omT + 324 * 384;          // 384x384
  u16* fc1T = oprojT + 384 * 384;         // 1536x384
  u16* fc2T = fc1T + 1536 * 384;          // 384x1536
  // R5: flag + canonical f32 params
  char* r5 = ws + 2 * SZ_NC2 + SZ_H1 + SZ_OM4 + 3197952;
  int* flag = (int*)r5;
  float* pf = (float*)r5;
  float* ln1_gF = pf + 16;
  float* ln1_bF = pf + 16 + 384;
  float* ln2_gF = pf + 16 + 768;
  float* ln2_bF = pf + 16 + 1152;
  float* vproj_bF = pf + 16 + 1536;
  float* om_bF = pf + 16 + 1920;      // 324
  float* oproj_bF = pf + 16 + 2304;
  float* fc1_bF = pf + 16 + 2688;     // 1536
  float* fc2_bF = pf + 16 + 4224;

  probe_kernel<<<1, 64, 0, stream>>>(ln1_g, flag);

  convert_vec<<<2, 256, 0, stream>>>(ln1_g, ln1_gF, 384, flag);
  convert_vec<<<2, 256, 0, stream>>>(ln1_b, ln1_bF, 384, flag);
  convert_vec<<<2, 256, 0, stream>>>(ln2_g, ln2_gF, 384, flag);
  convert_vec<<<2, 256, 0, stream>>>(ln2_b, ln2_bF, 384, flag);
  convert_vec<<<2, 256, 0, stream>>>(vproj_b, vproj_bF, 384, flag);
  convert_vec<<<2, 256, 0, stream>>>(om_b, om_bF, 324, flag);
  convert_vec<<<2, 256, 0, stream>>>(oproj_b, oproj_bF, 384, flag);
  convert_vec<<<6, 256, 0, stream>>>(fc1_b, fc1_bF, 1536, flag);
  convert_vec<<<2, 256, 0, stream>>>(fc2_b, fc2_bF, 384, flag);

  convert_wT<<<(384 * 96 + 255) / 256, 256, 0, stream>>>(vproj_w, vprojT, 384, 384, flag);
  convert_wT<<<(324 * 96 + 255) / 256, 256, 0, stream>>>(om_w, omT, 384, 324, flag);
  convert_wT<<<(384 * 96 + 255) / 256, 256, 0, stream>>>(oproj_w, oprojT, 384, 384, flag);
  convert_wT<<<(1536 * 96 + 255) / 256, 256, 0, stream>>>(fc1_w, fc1T, 384, 1536, flag);
  convert_wT<<<(384 * 384 + 255) / 256, 256, 0, stream>>>(fc2_w, fc2T, 1536, 384, flag);

  ln1_kernel<<<BB * 49, 256, 0, stream>>>(x, ln1_gF, ln1_bF, tn, flag);

  gemm_k<0, false><<<dim3(NT / 128, 3), 256, 0, stream>>>(
      tn, vprojT, vproj_bF, nullptr, val, NT, 384, 384, 0, flag);
  gemm_k<1, false><<<dim3(NT / 128, 3), 256, 0, stream>>>(
      tn, omT, om_bF, nullptr, om, NT, 324, 384, 0, flag);

  dcn_kernel<<<(NT * GG) / 8, 256, 0, stream>>>(val, om, dcn);

  gemm_k<2, false><<<dim3(NT / 128, 3), 256, 0, stream>>>(
      dcn, oprojT, oproj_bF, x, xp1, NT, 384, 384, 0, flag);

  ln2_kernel<<<NT / 4, 256, 0, stream>>>(xp1, ln2_gF, ln2_bF, y2);

  // fc1 + fc2 in 4 M-chunks (blocks 25,25,24,24); h reuses R1
  const int chunk_blocks[4] = {25, 25, 24, 24};
  int r0 = 0;
  for (int c = 0; c < 4; c++) {
    int nb = chunk_blocks[c];
    int rows = nb * 128;
    gemm_k<0, true><<<dim3(nb, 12), 256, 0, stream>>>(
        y2 + (size_t)r0 * CC, fc1T, fc1_bF, nullptr, h, rows, HID, 384, 0, flag);
    gemm_k<3, false><<<dim3(nb, 3), 256, 0, stream>>>(
        h, fc2T, fc2_bF, xp1, d_out, rows, 384, HID, r0, flag);
    r0 += rows;
  }
}

// Round 4
// 470.516 us; speedup vs baseline: 1.6958x; 1.6958x over previous
//
#include <hip/hip_runtime.h>
#include <math.h>

typedef unsigned short u16;
typedef unsigned int u32;
typedef __bf16 bf16x8 __attribute__((ext_vector_type(8)));
typedef float f32x4 __attribute__((ext_vector_type(4)));

// ---- problem constants ----
#define BB 4
#define CC 384
#define HH 56
#define WW 56
#define GG 12
#define GCC 32
#define KK 9
#define HWD 3136           // H*W
#define NT 12544           // B*H*W tokens
#define HID 1536
#define EPSV 1e-5f

__device__ __forceinline__ float b2f(u16 u) {
  union { float f; u32 u; } c; c.u = ((u32)u) << 16; return c.f;
}
__device__ __forceinline__ u16 f2b(float f) {
  union { float f; u32 u; } c; c.f = f;
  u32 r = c.u + 0x7FFFu + ((c.u >> 16) & 1u);
  return (u16)(r >> 16);
}

// =====================================================================
// Probe: ln1_g[0] == 1.0f exactly. f32 -> first u32 is 0x3F800000;
// bf16 pair (1.0,1.0) -> 0x3F803F80. flag=1 means f32 inputs.
// =====================================================================
__global__ void probe_kernel(const void* __restrict__ g, int* __restrict__ flag) {
  if (threadIdx.x == 0 && blockIdx.x == 0) {
    u32 u = *(const u32*)g;
    *flag = (u == 0x3F800000u) ? 1 : 0;
  }
}

// =====================================================================
// Fused param conversion: 9 vectors -> canonical f32 at fixed offsets.
// grid (6, 9); blockIdx.y selects segment.
// dst: ln1_g@0 ln1_b@384 ln2_g@768 ln2_b@1152 vproj_b@1536 om_b@1920
//      oproj_b@2304 fc1_b@2688 fc2_b@4224
// =====================================================================
__global__ void convert_params(
    const void* q0, const void* q1, const void* q2, const void* q3,
    const void* q4, const void* q5, const void* q6, const void* q7,
    const void* q8, float* __restrict__ dst, const int* __restrict__ flag) {
  const void* src; int off, n;
  switch (blockIdx.y) {
    case 0: src = q0; off = 0;    n = 384;  break;
    case 1: src = q1; off = 384;  n = 384;  break;
    case 2: src = q2; off = 768;  n = 384;  break;
    case 3: src = q3; off = 1152; n = 384;  break;
    case 4: src = q4; off = 1536; n = 384;  break;
    case 5: src = q5; off = 1920; n = 324;  break;
    case 6: src = q6; off = 2304; n = 384;  break;
    case 7: src = q7; off = 2688; n = 1536; break;
    default: src = q8; off = 4224; n = 384; break;
  }
  int i = blockIdx.x * 256 + threadIdx.x;
  if (i >= n) return;
  float v = (*flag) ? ((const float*)src)[i] : b2f(((const u16*)src)[i]);
  dst[off + i] = v;
}

// =====================================================================
// Fused weight convert+transpose: 5 weights (KxN) -> (NxK) bf16.
// grid (576, 5); blockIdx.y selects weight.
// =====================================================================
__global__ void convert_weights(
    const void* w0, const void* w1, const void* w2, const void* w3,
    const void* w4, u16* __restrict__ wT, const int* __restrict__ flag) {
  const void* in; u16* out; int K, N;
  switch (blockIdx.y) {
    case 0: in = w0; out = wT;                      K = 384;  N = 384;  break;
    case 1: in = w1; out = wT + 147456;             K = 384;  N = 324;  break;
    case 2: in = w2; out = wT + 147456 + 124416;    K = 384;  N = 384;  break;
    case 3: in = w3; out = wT + 2*147456 + 124416;  K = 384;  N = 1536; break;
    default: in = w4; out = wT + 2*147456 + 124416 + 589824; K = 1536; N = 384; break;
  }
  int idx = blockIdx.x * 256 + threadIdx.x;
  int kq = K >> 2;
  if (idx >= N * kq) return;
  int n = idx / kq;
  int k4 = (idx - n * kq) << 2;
  u16 e[4];
  if (*flag) {
    const float* f = (const float*)in;
#pragma unroll
    for (int r = 0; r < 4; r++) e[r] = f2b(f[(size_t)(k4 + r) * N + n]);
  } else {
    const u16* hh = (const u16*)in;
#pragma unroll
    for (int r = 0; r < 4; r++) e[r] = hh[(size_t)(k4 + r) * N + n];
  }
  uint2 pk;
  pk.x = (u32)e[0] | ((u32)e[1] << 16);
  pk.y = (u32)e[2] | ((u32)e[3] << 16);
  *reinterpret_cast<uint2*>(&out[(size_t)n * K + k4]) = pk;
}

// =====================================================================
// LN1 + NCHW->NHWC transpose. x: (B,C,HW) (bf16|f32) -> tn: (NT,C) bf16
// =====================================================================
__global__ __launch_bounds__(256) void ln1_kernel(
    const void* __restrict__ x, const float* __restrict__ gam,
    const float* __restrict__ bet, u16* __restrict__ tn,
    const int* __restrict__ flag) {
  __shared__ u16 tile[64 * 385];
  const int t = threadIdx.x;
  const int blk = blockIdx.x;
  const int b = blk / 49;
  const int hw0 = (blk - b * 49) * 64;
  const int dtf = *flag;

  const int cofs = t >> 3;        // 0..31
  const int hofs = (t & 7) * 8;   // 0..56
  if (dtf) {
    const float* xf = (const float*)x;
#pragma unroll
    for (int it = 0; it < 12; it++) {
      int cc = it * 32 + cofs;
      size_t base = ((size_t)b * CC + cc) * HWD + hw0 + hofs;
      float4 a0 = *reinterpret_cast<const float4*>(&xf[base]);
      float4 a1 = *reinterpret_cast<const float4*>(&xf[base + 4]);
      tile[(hofs + 0) * 385 + cc] = f2b(a0.x);
      tile[(hofs + 1) * 385 + cc] = f2b(a0.y);
      tile[(hofs + 2) * 385 + cc] = f2b(a0.z);
      tile[(hofs + 3) * 385 + cc] = f2b(a0.w);
      tile[(hofs + 4) * 385 + cc] = f2b(a1.x);
      tile[(hofs + 5) * 385 + cc] = f2b(a1.y);
      tile[(hofs + 6) * 385 + cc] = f2b(a1.z);
      tile[(hofs + 7) * 385 + cc] = f2b(a1.w);
    }
  } else {
    const u16* xh = (const u16*)x;
#pragma unroll
    for (int it = 0; it < 12; it++) {
      int cc = it * 32 + cofs;
      uint4 v = *reinterpret_cast<const uint4*>(
          &xh[((size_t)b * CC + cc) * HWD + hw0 + hofs]);
      u32 uu[4] = {v.x, v.y, v.z, v.w};
#pragma unroll
      for (int r = 0; r < 4; r++) {
        tile[(hofs + 2 * r + 0) * 385 + cc] = (u16)(uu[r] & 0xFFFFu);
        tile[(hofs + 2 * r + 1) * 385 + cc] = (u16)(uu[r] >> 16);
      }
    }
  }
  __syncthreads();

  const int lane = t & 63;
  const int wv = t >> 6;
  for (int tk = wv; tk < 64; tk += 4) {
    float v[6];
    float s = 0.f;
#pragma unroll
    for (int j = 0; j < 6; j++) {
      v[j] = b2f(tile[tk * 385 + j * 64 + lane]);
      s += v[j];
    }
#pragma unroll
    for (int off = 32; off > 0; off >>= 1) s += __shfl_xor(s, off);
    float mu = s * (1.f / 384.f);
    float q = 0.f;
#pragma unroll
    for (int j = 0; j < 6; j++) {
      float d = v[j] - mu;
      q += d * d;
    }
#pragma unroll
    for (int off = 32; off > 0; off >>= 1) q += __shfl_xor(q, off);
    float rs = rsqrtf(q * (1.f / 384.f) + EPSV);
    size_t row = ((size_t)b * HWD + hw0 + tk) * CC;
#pragma unroll
    for (int j = 0; j < 6; j++) {
      int cc = j * 64 + lane;
      float y = (v[j] - mu) * rs * gam[cc] + bet[cc];
      tn[row + cc] = f2b(y);
    }
  }
}

// =====================================================================
// LN2: xp1 (NT,C) bf16 -> y2 (NT,C) bf16. One wave per token.
// =====================================================================
__global__ __launch_bounds__(256) void ln2_kernel(
    const u16* __restrict__ xp1, const float* __restrict__ gam,
    const float* __restrict__ bet, u16* __restrict__ y2) {
  const int tok = blockIdx.x * 4 + (threadIdx.x >> 6);
  const int lane = threadIdx.x & 63;
  const u16* row = xp1 + (size_t)tok * CC;
  float v[6];
  float s = 0.f;
#pragma unroll
  for (int j = 0; j < 6; j++) {
    v[j] = b2f(row[j * 64 + lane]);
    s += v[j];
  }
#pragma unroll
  for (int off = 32; off > 0; off >>= 1) s += __shfl_xor(s, off);
  float mu = s * (1.f / 384.f);
  float q = 0.f;
#pragma unroll
  for (int j = 0; j < 6; j++) {
    float d = v[j] - mu;
    q += d * d;
  }
#pragma unroll
  for (int off = 32; off > 0; off >>= 1) q += __shfl_xor(q, off);
  float rs = rsqrtf(q * (1.f / 384.f) + EPSV);
#pragma unroll
  for (int j = 0; j < 6; j++) {
    int cc = j * 64 + lane;
    y2[(size_t)tok * CC + cc] = f2b((v[j] - mu) * rs * gam[cc] + bet[cc]);
  }
}

// =====================================================================
// DCNv4 sampling, latency-optimized.
// 16 lanes per (b,hw,g) group; each lane handles 2 channels (u32 loads).
// om preloaded via 7 x float4 (4B-aligned multi-dword loads are legal),
// so all 36 corner loads are independent -> pipelined, no per-k chain.
// =====================================================================
__global__ __launch_bounds__(256) void dcn_kernel(
    const u16* __restrict__ val, const float* __restrict__ om,
    u16* __restrict__ dcn) {
  const int t = threadIdx.x;
  const int u = blockIdx.x * 16 + (t >> 4);
  const int l = t & 15;            // 2 channels per lane
  const int g = u % GG;
  const int bhw = u / GG;
  const int hw = bhw % HWD;
  const int b = bhw / HWD;
  const int wx = hw % WW;
  const int hy = hw / WW;

  const float* o = om + (size_t)bhw * 324 + g * 27;
  float4 q[7];
#pragma unroll
  for (int i = 0; i < 7; i++)
    q[i] = *reinterpret_cast<const float4*>(o + 4 * i);
  float ov[28];
#pragma unroll
  for (int i = 0; i < 7; i++) {
    ov[4 * i + 0] = q[i].x;
    ov[4 * i + 1] = q[i].y;
    ov[4 * i + 2] = q[i].z;
    ov[4 * i + 3] = q[i].w;
  }

  const u16* vb = val + (size_t)b * HWD * CC + g * GCC + l * 2;
  float acc0 = 0.f, acc1 = 0.f;
#pragma unroll
  for (int k = 0; k < KK; k++) {
    float dx = ov[2 * k];
    float dy = ov[2 * k + 1];
    float mw = ov[18 + k];
    float px = (float)(wx + (k % 3) - 1) + dx;
    float py = (float)(hy + (k / 3) - 1) + dy;
    float x0f = floorf(px), y0f = floorf(py);
    float tx = px - x0f, ty = py - y0f;
    int x0 = (int)x0f, y0 = (int)y0f;
    int x1 = x0 + 1, y1 = y0 + 1;
    bool xv0 = (x0 >= 0) && (x0 < WW);
    bool xv1 = (x1 >= 0) && (x1 < WW);
    bool yv0 = (y0 >= 0) && (y0 < HH);
    bool yv1 = (y1 >= 0) && (y1 < HH);
    int xc0 = min(max(x0, 0), WW - 1), xc1 = min(max(x1, 0), WW - 1);
    int yc0 = min(max(y0, 0), HH - 1), yc1 = min(max(y1, 0), HH - 1);
    u32 c00 = *reinterpret_cast<const u32*>(&vb[(size_t)(yc0 * WW + xc0) * CC]);
    u32 c01 = *reinterpret_cast<const u32*>(&vb[(size_t)(yc0 * WW + xc1) * CC]);
    u32 c10 = *reinterpret_cast<const u32*>(&vb[(size_t)(yc1 * WW + xc0) * CC]);
    u32 c11 = *reinterpret_cast<const u32*>(&vb[(size_t)(yc1 * WW + xc1) * CC]);
    float w00 = (yv0 && xv0) ? (1.f - tx) * (1.f - ty) : 0.f;
    float w01 = (yv0 && xv1) ? tx * (1.f - ty) : 0.f;
    float w10 = (yv1 && xv0) ? (1.f - tx) * ty : 0.f;
    float w11 = (yv1 && xv1) ? tx * ty : 0.f;
    float s0 = w00 * b2f((u16)(c00 & 0xFFFFu)) + w01 * b2f((u16)(c01 & 0xFFFFu)) +
               w10 * b2f((u16)(c10 & 0xFFFFu)) + w11 * b2f((u16)(c11 & 0xFFFFu));
    float s1 = w00 * b2f((u16)(c00 >> 16)) + w01 * b2f((u16)(c01 >> 16)) +
               w10 * b2f((u16)(c10 >> 16)) + w11 * b2f((u16)(c11 >> 16));
    acc0 += mw * s0;
    acc1 += mw * s1;
  }
  u32 pk = (u32)f2b(acc0) | ((u32)f2b(acc1) << 16);
  *reinterpret_cast<u32*>(&dcn[(size_t)bhw * CC + g * GCC + l * 2]) = pk;
}

// =====================================================================
// GEMM: out(M,N) = A(M,K) @ W(K,N) + bias(f32), Wt (N,K) bf16.
// 128x128 tile, 4 waves of 64x64, BK=32, mfma_f32_16x16x32_bf16.
// MODE 0: bf16 out (row-major M x N), N-guarded.
// MODE 1: f32 out, N-guarded.
// MODE 2: bf16 out + residual from external x in NCHW (dtype per flag).
// MODE 3: external out (NCHW, dtype per flag) + bf16 residual (xp1); moff.
// =====================================================================
template <int MODE, bool GELU>
__global__ __launch_bounds__(256) void gemm_k(
    const u16* __restrict__ A, const u16* __restrict__ Wt,
    const float* __restrict__ bias, const void* __restrict__ res,
    void* __restrict__ out, int M, int N, int K, int moff,
    const int* __restrict__ flag) {
  __shared__ u16 As[128 * 40];
  __shared__ u16 Bs[128 * 40];
  const int t = threadIdx.x;
  const int m0 = blockIdx.x * 128;
  const int n0 = blockIdx.y * 128;
  const int sr = t >> 3;          // 0..31
  const int sc = (t & 7) << 2;    // 0..28
  const int lane = t & 63;
  const int wv = t >> 6;
  const int wm = (wv >> 1) << 6;
  const int wn = (wv & 1) << 6;
  const int fr = lane & 15;
  const int quad = lane >> 4;
  const int dtf = (MODE >= 2) ? *flag : 0;

  f32x4 acc[4][4];
#pragma unroll
  for (int mi = 0; mi < 4; mi++)
#pragma unroll
    for (int ni = 0; ni < 4; ni++) acc[mi][ni] = f32x4{0.f, 0.f, 0.f, 0.f};

  for (int kb = 0; kb < K; kb += 32) {
    __syncthreads();
#pragma unroll
    for (int i = 0; i < 4; i++) {
      int r = (i << 5) + sr;
      *reinterpret_cast<uint2*>(&As[r * 40 + sc]) =
          *reinterpret_cast<const uint2*>(&A[(size_t)(m0 + r) * K + kb + sc]);
    }
#pragma unroll
    for (int i = 0; i < 4; i++) {
      int r = (i << 5) + sr;
      uint2 v = make_uint2(0u, 0u);
      if (n0 + r < N)
        v = *reinterpret_cast<const uint2*>(&Wt[(size_t)(n0 + r) * K + kb + sc]);
      *reinterpret_cast<uint2*>(&Bs[r * 40 + sc]) = v;
    }
    __syncthreads();
    bf16x8 av[4], bv[4];
#pragma unroll
    for (int mi = 0; mi < 4; mi++)
      av[mi] = *reinterpret_cast<const bf16x8*>(
          &As[(wm + mi * 16 + fr) * 40 + quad * 8]);
#pragma unroll
    for (int ni = 0; ni < 4; ni++)
      bv[ni] = *reinterpret_cast<const bf16x8*>(
          &Bs[(wn + ni * 16 + fr) * 40 + quad * 8]);
#pragma unroll
    for (int mi = 0; mi < 4; mi++)
#pragma unroll
      for (int ni = 0; ni < 4; ni++)
        acc[mi][ni] = __builtin_amdgcn_mfma_f32_16x16x32_bf16(
            av[mi], bv[ni], acc[mi][ni], 0, 0, 0);
  }

  // epilogue
  float bias_v[4];
#pragma unroll
  for (int ni = 0; ni < 4; ni++) {
    int n = n0 + wn + ni * 16 + fr;
    bias_v[ni] = (n < N) ? bias[n] : 0.f;
  }
#pragma unroll
  for (int mi = 0; mi < 4; mi++) {
#pragma unroll
    for (int ni = 0; ni < 4; ni++) {
      int n = n0 + wn + ni * 16 + fr;
      int mbase = m0 + wm + mi * 16 + quad * 4;
      if (MODE == 3) {
        const u16* rf = (const u16*)res;
        int mg = mbase + moff;
        int b = mg / HWD;
        int hw = mg - b * HWD;
        float vv[4];
#pragma unroll
        for (int r = 0; r < 4; r++)
          vv[r] = acc[mi][ni][r] + bias_v[ni] + b2f(rf[(size_t)(mg + r) * CC + n]);
        if (dtf) {
          float4 st = make_float4(vv[0], vv[1], vv[2], vv[3]);
          *reinterpret_cast<float4*>(
              &((float*)out)[((size_t)b * CC + n) * HWD + hw]) = st;
        } else {
          uint2 st;
          st.x = (u32)f2b(vv[0]) | ((u32)f2b(vv[1]) << 16);
          st.y = (u32)f2b(vv[2]) | ((u32)f2b(vv[3]) << 16);
          *reinterpret_cast<uint2*>(
              &((u16*)out)[((size_t)b * CC + n) * HWD + hw]) = st;
        }
      } else if (MODE == 2) {
        int b = mbase / HWD;
        int hw = mbase - b * HWD;
        float rv[4];
        if (dtf) {
          const float* xf = (const float*)res;
          float4 q = *reinterpret_cast<const float4*>(
              &xf[((size_t)b * CC + n) * HWD + hw]);
          rv[0] = q.x; rv[1] = q.y; rv[2] = q.z; rv[3] = q.w;
        } else {
          const u16* xh = (const u16*)res;
          uint2 q = *reinterpret_cast<const uint2*>(
              &xh[((size_t)b * CC + n) * HWD + hw]);
          rv[0] = b2f((u16)(q.x & 0xFFFFu));
          rv[1] = b2f((u16)(q.x >> 16));
          rv[2] = b2f((u16)(q.y & 0xFFFFu));
          rv[3] = b2f((u16)(q.y >> 16));
        }
#pragma unroll
        for (int r = 0; r < 4; r++) {
          float vv = acc[mi][ni][r] + bias_v[ni] + rv[r];
          ((u16*)out)[(size_t)(mbase + r) * CC + n] = f2b(vv);
        }
      } else {
#pragma unroll
        for (int r = 0; r < 4; r++) {
          int m = mbase + r;
          float vv = acc[mi][ni][r] + bias_v[ni];
          if (GELU) vv = 0.5f * vv * (1.0f + erff(vv * 0.70710678118654752f));
          if (MODE == 0) {
            if (n < N) ((u16*)out)[(size_t)m * N + n] = f2b(vv);
          } else if (MODE == 1) {
            if (n < N) ((float*)out)[(size_t)m * N + n] = vv;
          }
        }
      }
    }
  }
}

// =====================================================================
extern "C" void kernel_launch(void* const* d_in, const int* in_sizes, int n_in,
                              void* d_out, int out_size, void* d_ws,
                              size_t ws_size, hipStream_t stream) {
  const void* x = d_in[0];
  const void* ln1_g = d_in[1];
  const void* ln1_b = d_in[2];
  const void* vproj_w = d_in[3];
  const void* vproj_b = d_in[4];
  const void* om_w = d_in[5];
  const void* om_b = d_in[6];
  const void* oproj_w = d_in[7];
  const void* oproj_b = d_in[8];
  const void* ln2_g = d_in[9];
  const void* ln2_b = d_in[10];
  const void* fc1_w = d_in[11];
  const void* fc1_b = d_in[12];
  const void* fc2_w = d_in[13];
  const void* fc2_b = d_in[14];

  char* ws = (char*)d_ws;
  const size_t SZ_NC2 = (size_t)NT * CC * 2;         // 9,633,792
  const size_t SZ_OM4 = (size_t)NT * 324 * 4;        // 16,257,024
  // R0: tn -> dcn -> y2            [0, NC2)
  // R1: val -> h (h spans R1+R2)   [NC2, 2*NC2)
  // R2: om f32                     [2*NC2, 2*NC2+OM4)   (h needs 19.3MB <= NC2+OM4)
  // R3: xp1 bf16                   [2*NC2+OM4, 3*NC2+OM4)
  // R4: weights bf16 (3,197,952 B)
  // R5: flag + canonical f32 params
  u16* tn = (u16*)(ws);
  u16* dcn = tn;
  u16* y2 = tn;
  u16* val = (u16*)(ws + SZ_NC2);
  u16* h = val;
  float* om = (float*)(ws + 2 * SZ_NC2);
  u16* xp1 = (u16*)(ws + 2 * SZ_NC2 + SZ_OM4);
  u16* wT = (u16*)(ws + 3 * SZ_NC2 + SZ_OM4);
  u16* vprojT = wT;
  u16* omT = vprojT + 147456;
  u16* oprojT = omT + 124416;
  u16* fc1T = oprojT + 147456;
  u16* fc2T = fc1T + 589824;
  char* r5 = ws + 3 * SZ_NC2 + SZ_OM4 + 3197952;
  int* flag = (int*)r5;
  float* pf = (float*)r5 + 16;
  float* ln1_gF = pf + 0;
  float* ln1_bF = pf + 384;
  float* ln2_gF = pf + 768;
  float* ln2_bF = pf + 1152;
  float* vproj_bF = pf + 1536;
  float* om_bF = pf + 1920;
  float* oproj_bF = pf + 2304;
  float* fc1_bF = pf + 2688;
  float* fc2_bF = pf + 4224;

  probe_kernel<<<1, 64, 0, stream>>>(ln1_g, flag);

  convert_params<<<dim3(6, 9), 256, 0, stream>>>(
      ln1_g, ln1_b, ln2_g, ln2_b, vproj_b, om_b, oproj_b, fc1_b, fc2_b,
      pf, flag);

  convert_weights<<<dim3(576, 5), 256, 0, stream>>>(
      vproj_w, om_w, oproj_w, fc1_w, fc2_w, wT, flag);

  ln1_kernel<<<BB * 49, 256, 0, stream>>>(x, ln1_gF, ln1_bF, tn, flag);

  gemm_k<0, false><<<dim3(NT / 128, 3), 256, 0, stream>>>(
      tn, vprojT, vproj_bF, nullptr, val, NT, 384, 384, 0, flag);
  gemm_k<1, false><<<dim3(NT / 128, 3), 256, 0, stream>>>(
      tn, omT, om_bF, nullptr, om, NT, 324, 384, 0, flag);

  dcn_kernel<<<(NT * GG) / 16, 256, 0, stream>>>(val, om, dcn);

  gemm_k<2, false><<<dim3(NT / 128, 3), 256, 0, stream>>>(
      dcn, oprojT, oproj_bF, x, xp1, NT, 384, 384, 0, flag);

  ln2_kernel<<<NT / 4, 256, 0, stream>>>(xp1, ln2_gF, ln2_bF, y2);

  // fc1 + fc2 in 2 M-chunks of 6272 rows; h overlays R1+R2
  for (int c = 0; c < 2; c++) {
    int r0 = c * 6272;
    gemm_k<0, true><<<dim3(49, 12), 256, 0, stream>>>(
        y2 + (size_t)r0 * CC, fc1T, fc1_bF, nullptr, h, 6272, HID, 384, 0, flag);
    gemm_k<3, false><<<dim3(49, 3), 256, 0, stream>>>(
        h, fc2T, fc2_bF, xp1, d_out, 6272, 384, HID, r0, flag);
  }
}

// Round 5
// 418.648 us; speedup vs baseline: 1.9059x; 1.1239x over previous
//
#include <hip/hip_runtime.h>
#include <math.h>

typedef unsigned short u16;
typedef unsigned int u32;
typedef __bf16 bf16x8 __attribute__((ext_vector_type(8)));
typedef float f32x4 __attribute__((ext_vector_type(4)));

// ---- problem constants ----
#define BB 4
#define CC 384
#define HH 56
#define WW 56
#define GG 12
#define GCC 32
#define KK 9
#define HWD 3136           // H*W
#define NT 12544           // B*H*W tokens
#define HID 1536
#define EPSV 1e-5f

__device__ __forceinline__ float b2f(u16 u) {
  union { float f; u32 u; } c; c.u = ((u32)u) << 16; return c.f;
}
__device__ __forceinline__ u16 f2b(float f) {
  union { float f; u32 u; } c; c.f = f;
  u32 r = c.u + 0x7FFFu + ((c.u >> 16) & 1u);
  return (u16)(r >> 16);
}

// =====================================================================
// Probe: ln1_g[0] == 1.0f exactly. f32 -> first u32 is 0x3F800000;
// bf16 pair (1.0,1.0) -> 0x3F803F80. flag=1 means f32 inputs.
// =====================================================================
__global__ void probe_kernel(const void* __restrict__ g, int* __restrict__ flag) {
  if (threadIdx.x == 0 && blockIdx.x == 0) {
    u32 u = *(const u32*)g;
    *flag = (u == 0x3F800000u) ? 1 : 0;
  }
}

// =====================================================================
// Fused param conversion: 9 vectors -> canonical f32 at fixed offsets.
// dst: ln1_g@0 ln1_b@384 ln2_g@768 ln2_b@1152 vproj_b@1536 om_b@1920
//      oproj_b@2304 fc1_b@2688 fc2_b@4224
// NOTE: vproj_b@1536 and om_b@1920 are contiguous -> fused 708-float bias.
// =====================================================================
__global__ void convert_params(
    const void* q0, const void* q1, const void* q2, const void* q3,
    const void* q4, const void* q5, const void* q6, const void* q7,
    const void* q8, float* __restrict__ dst, const int* __restrict__ flag) {
  const void* src; int off, n;
  switch (blockIdx.y) {
    case 0: src = q0; off = 0;    n = 384;  break;
    case 1: src = q1; off = 384;  n = 384;  break;
    case 2: src = q2; off = 768;  n = 384;  break;
    case 3: src = q3; off = 1152; n = 384;  break;
    case 4: src = q4; off = 1536; n = 384;  break;
    case 5: src = q5; off = 1920; n = 324;  break;
    case 6: src = q6; off = 2304; n = 384;  break;
    case 7: src = q7; off = 2688; n = 1536; break;
    default: src = q8; off = 4224; n = 384; break;
  }
  int i = blockIdx.x * 256 + threadIdx.x;
  if (i >= n) return;
  float v = (*flag) ? ((const float*)src)[i] : b2f(((const u16*)src)[i]);
  dst[off + i] = v;
}

// =====================================================================
// Fused weight convert+transpose: 5 weights (KxN) -> (NxK) bf16.
// Layout keeps vprojT then omT contiguous (fused 708-row B for GEMM 1).
// =====================================================================
__global__ void convert_weights(
    const void* w0, const void* w1, const void* w2, const void* w3,
    const void* w4, u16* __restrict__ wT, const int* __restrict__ flag) {
  const void* in; u16* out; int K, N;
  switch (blockIdx.y) {
    case 0: in = w0; out = wT;                      K = 384;  N = 384;  break;
    case 1: in = w1; out = wT + 147456;             K = 384;  N = 324;  break;
    case 2: in = w2; out = wT + 147456 + 124416;    K = 384;  N = 384;  break;
    case 3: in = w3; out = wT + 2*147456 + 124416;  K = 384;  N = 1536; break;
    default: in = w4; out = wT + 2*147456 + 124416 + 589824; K = 1536; N = 384; break;
  }
  int idx = blockIdx.x * 256 + threadIdx.x;
  int kq = K >> 2;
  if (idx >= N * kq) return;
  int n = idx / kq;
  int k4 = (idx - n * kq) << 2;
  u16 e[4];
  if (*flag) {
    const float* f = (const float*)in;
#pragma unroll
    for (int r = 0; r < 4; r++) e[r] = f2b(f[(size_t)(k4 + r) * N + n]);
  } else {
    const u16* hh = (const u16*)in;
#pragma unroll
    for (int r = 0; r < 4; r++) e[r] = hh[(size_t)(k4 + r) * N + n];
  }
  uint2 pk;
  pk.x = (u32)e[0] | ((u32)e[1] << 16);
  pk.y = (u32)e[2] | ((u32)e[3] << 16);
  *reinterpret_cast<uint2*>(&out[(size_t)n * K + k4]) = pk;
}

// =====================================================================
// LN1 + NCHW->NHWC transpose. x: (B,C,HW) (bf16|f32) -> tn: (NT,C) bf16
// =====================================================================
__global__ __launch_bounds__(256) void ln1_kernel(
    const void* __restrict__ x, const float* __restrict__ gam,
    const float* __restrict__ bet, u16* __restrict__ tn,
    const int* __restrict__ flag) {
  __shared__ u16 tile[64 * 385];
  const int t = threadIdx.x;
  const int blk = blockIdx.x;
  const int b = blk / 49;
  const int hw0 = (blk - b * 49) * 64;
  const int dtf = *flag;

  const int cofs = t >> 3;        // 0..31
  const int hofs = (t & 7) * 8;   // 0..56
  if (dtf) {
    const float* xf = (const float*)x;
#pragma unroll
    for (int it = 0; it < 12; it++) {
      int cc = it * 32 + cofs;
      size_t base = ((size_t)b * CC + cc) * HWD + hw0 + hofs;
      float4 a0 = *reinterpret_cast<const float4*>(&xf[base]);
      float4 a1 = *reinterpret_cast<const float4*>(&xf[base + 4]);
      tile[(hofs + 0) * 385 + cc] = f2b(a0.x);
      tile[(hofs + 1) * 385 + cc] = f2b(a0.y);
      tile[(hofs + 2) * 385 + cc] = f2b(a0.z);
      tile[(hofs + 3) * 385 + cc] = f2b(a0.w);
      tile[(hofs + 4) * 385 + cc] = f2b(a1.x);
      tile[(hofs + 5) * 385 + cc] = f2b(a1.y);
      tile[(hofs + 6) * 385 + cc] = f2b(a1.z);
      tile[(hofs + 7) * 385 + cc] = f2b(a1.w);
    }
  } else {
    const u16* xh = (const u16*)x;
#pragma unroll
    for (int it = 0; it < 12; it++) {
      int cc = it * 32 + cofs;
      uint4 v = *reinterpret_cast<const uint4*>(
          &xh[((size_t)b * CC + cc) * HWD + hw0 + hofs]);
      u32 uu[4] = {v.x, v.y, v.z, v.w};
#pragma unroll
      for (int r = 0; r < 4; r++) {
        tile[(hofs + 2 * r + 0) * 385 + cc] = (u16)(uu[r] & 0xFFFFu);
        tile[(hofs + 2 * r + 1) * 385 + cc] = (u16)(uu[r] >> 16);
      }
    }
  }
  __syncthreads();

  const int lane = t & 63;
  const int wv = t >> 6;
  for (int tk = wv; tk < 64; tk += 4) {
    float v[6];
    float s = 0.f;
#pragma unroll
    for (int j = 0; j < 6; j++) {
      v[j] = b2f(tile[tk * 385 + j * 64 + lane]);
      s += v[j];
    }
#pragma unroll
    for (int off = 32; off > 0; off >>= 1) s += __shfl_xor(s, off);
    float mu = s * (1.f / 384.f);
    float q = 0.f;
#pragma unroll
    for (int j = 0; j < 6; j++) {
      float d = v[j] - mu;
      q += d * d;
    }
#pragma unroll
    for (int off = 32; off > 0; off >>= 1) q += __shfl_xor(q, off);
    float rs = rsqrtf(q * (1.f / 384.f) + EPSV);
    size_t row = ((size_t)b * HWD + hw0 + tk) * CC;
#pragma unroll
    for (int j = 0; j < 6; j++) {
      int cc = j * 64 + lane;
      float y = (v[j] - mu) * rs * gam[cc] + bet[cc];
      tn[row + cc] = f2b(y);
    }
  }
}

// =====================================================================
// LN2: xp1 (NT,C) bf16 -> y2 (NT,C) bf16. One wave per token.
// =====================================================================
__global__ __launch_bounds__(256) void ln2_kernel(
    const u16* __restrict__ xp1, const float* __restrict__ gam,
    const float* __restrict__ bet, u16* __restrict__ y2) {
  const int tok = blockIdx.x * 4 + (threadIdx.x >> 6);
  const int lane = threadIdx.x & 63;
  const u16* row = xp1 + (size_t)tok * CC;
  float v[6];
  float s = 0.f;
#pragma unroll
  for (int j = 0; j < 6; j++) {
    v[j] = b2f(row[j * 64 + lane]);
    s += v[j];
  }
#pragma unroll
  for (int off = 32; off > 0; off >>= 1) s += __shfl_xor(s, off);
  float mu = s * (1.f / 384.f);
  float q = 0.f;
#pragma unroll
  for (int j = 0; j < 6; j++) {
    float d = v[j] - mu;
    q += d * d;
  }
#pragma unroll
  for (int off = 32; off > 0; off >>= 1) q += __shfl_xor(q, off);
  float rs = rsqrtf(q * (1.f / 384.f) + EPSV);
#pragma unroll
  for (int j = 0; j < 6; j++) {
    int cc = j * 64 + lane;
    y2[(size_t)tok * CC + cc] = f2b((v[j] - mu) * rs * gam[cc] + bet[cc]);
  }
}

// =====================================================================
// DCNv4 sampling, latency-optimized (16 lanes/group, 2 ch/lane,
// om preloaded as 7 x float4 -> all 36 corner loads independent).
// =====================================================================
__global__ __launch_bounds__(256) void dcn_kernel(
    const u16* __restrict__ val, const float* __restrict__ om,
    u16* __restrict__ dcn) {
  const int t = threadIdx.x;
  const int u = blockIdx.x * 16 + (t >> 4);
  const int l = t & 15;
  const int g = u % GG;
  const int bhw = u / GG;
  const int hw = bhw % HWD;
  const int b = bhw / HWD;
  const int wx = hw % WW;
  const int hy = hw / WW;

  const float* o = om + (size_t)bhw * 324 + g * 27;
  float4 q[7];
#pragma unroll
  for (int i = 0; i < 7; i++)
    q[i] = *reinterpret_cast<const float4*>(o + 4 * i);
  float ov[28];
#pragma unroll
  for (int i = 0; i < 7; i++) {
    ov[4 * i + 0] = q[i].x;
    ov[4 * i + 1] = q[i].y;
    ov[4 * i + 2] = q[i].z;
    ov[4 * i + 3] = q[i].w;
  }

  const u16* vb = val + (size_t)b * HWD * CC + g * GCC + l * 2;
  float acc0 = 0.f, acc1 = 0.f;
#pragma unroll
  for (int k = 0; k < KK; k++) {
    float dx = ov[2 * k];
    float dy = ov[2 * k + 1];
    float mw = ov[18 + k];
    float px = (float)(wx + (k % 3) - 1) + dx;
    float py = (float)(hy + (k / 3) - 1) + dy;
    float x0f = floorf(px), y0f = floorf(py);
    float tx = px - x0f, ty = py - y0f;
    int x0 = (int)x0f, y0 = (int)y0f;
    int x1 = x0 + 1, y1 = y0 + 1;
    bool xv0 = (x0 >= 0) && (x0 < WW);
    bool xv1 = (x1 >= 0) && (x1 < WW);
    bool yv0 = (y0 >= 0) && (y0 < HH);
    bool yv1 = (y1 >= 0) && (y1 < HH);
    int xc0 = min(max(x0, 0), WW - 1), xc1 = min(max(x1, 0), WW - 1);
    int yc0 = min(max(y0, 0), HH - 1), yc1 = min(max(y1, 0), HH - 1);
    u32 c00 = *reinterpret_cast<const u32*>(&vb[(size_t)(yc0 * WW + xc0) * CC]);
    u32 c01 = *reinterpret_cast<const u32*>(&vb[(size_t)(yc0 * WW + xc1) * CC]);
    u32 c10 = *reinterpret_cast<const u32*>(&vb[(size_t)(yc1 * WW + xc0) * CC]);
    u32 c11 = *reinterpret_cast<const u32*>(&vb[(size_t)(yc1 * WW + xc1) * CC]);
    float w00 = (yv0 && xv0) ? (1.f - tx) * (1.f - ty) : 0.f;
    float w01 = (yv0 && xv1) ? tx * (1.f - ty) : 0.f;
    float w10 = (yv1 && xv0) ? (1.f - tx) * ty : 0.f;
    float w11 = (yv1 && xv1) ? tx * ty : 0.f;
    float s0 = w00 * b2f((u16)(c00 & 0xFFFFu)) + w01 * b2f((u16)(c01 & 0xFFFFu)) +
               w10 * b2f((u16)(c10 & 0xFFFFu)) + w11 * b2f((u16)(c11 & 0xFFFFu));
    float s1 = w00 * b2f((u16)(c00 >> 16)) + w01 * b2f((u16)(c01 >> 16)) +
               w10 * b2f((u16)(c10 >> 16)) + w11 * b2f((u16)(c11 >> 16));
    acc0 += mw * s0;
    acc1 += mw * s1;
  }
  u32 pk = (u32)f2b(acc0) | ((u32)f2b(acc1) << 16);
  *reinterpret_cast<u32*>(&dcn[(size_t)bhw * CC + g * GCC + l * 2]) = pk;
}

// =====================================================================
// Barrier-free wave-GEMM: each wave owns a 64x64 tile; A/B fragments
// loaded straight from global (16B/lane, coalesced 64B segments).
// No LDS, no __syncthreads -> compiler pipelines loads across K-steps
// and 16 independent waves/CU hide latency. Tiles ordered n-fastest so
// a block's 4 waves share the same A strip (L1/L2 reuse).
// A (M,K) bf16, Wt (N,K) bf16, bias f32.
// MODE 4: fused vproj+om. n<384 -> out=val bf16 (ld 384);
//         384<=n<708 -> out2=om f32 (ld 324). Nn=708 guard.
// MODE 2: bf16 out (xp1, ld 384) + residual from external NCHW x (dtf).
// MODE 0: bf16 out (ld Nn), optional GELU.
// MODE 3: external NCHW out (dtf) + bf16 residual xp1 (ld 384); moff.
// =====================================================================
template <int MODE, bool GELU>
__global__ __launch_bounds__(256) void wgemm_k(
    const u16* __restrict__ A, const u16* __restrict__ Wt,
    const float* __restrict__ bias, const void* __restrict__ res,
    void* __restrict__ out, void* __restrict__ out2,
    int Mt, int Ntiles, int Nn, int K, int moff,
    const int* __restrict__ flag) {
  const int t = threadIdx.x;
  const int wv = t >> 6;
  const int lane = t & 63;
  const int fr = lane & 15;
  const int quad = lane >> 4;
  const int tile = blockIdx.x * 4 + wv;
  const int mt = tile / Ntiles;
  const int nt = tile - mt * Ntiles;
  if (mt >= Mt) return;
  const int m0 = mt << 6;
  const int n0 = nt << 6;
  const int dtf = (MODE == 2 || MODE == 3) ? *flag : 0;

  f32x4 acc[4][4];
#pragma unroll
  for (int mi = 0; mi < 4; mi++)
#pragma unroll
    for (int ni = 0; ni < 4; ni++) acc[mi][ni] = f32x4{0.f, 0.f, 0.f, 0.f};

  const u16* Ap = A + (size_t)(m0 + fr) * K + quad * 8;
  const u16* Bp = Wt + (size_t)(n0 + fr) * K + quad * 8;

  for (int kb = 0; kb < K; kb += 32) {
    bf16x8 av[4], bv[4];
#pragma unroll
    for (int mi = 0; mi < 4; mi++)
      av[mi] = *reinterpret_cast<const bf16x8*>(Ap + (size_t)(mi * 16) * K + kb);
#pragma unroll
    for (int ni = 0; ni < 4; ni++)
      bv[ni] = *reinterpret_cast<const bf16x8*>(Bp + (size_t)(ni * 16) * K + kb);
#pragma unroll
    for (int mi = 0; mi < 4; mi++)
#pragma unroll
      for (int ni = 0; ni < 4; ni++)
        acc[mi][ni] = __builtin_amdgcn_mfma_f32_16x16x32_bf16(
            av[mi], bv[ni], acc[mi][ni], 0, 0, 0);
  }

  float bias_v[4];
#pragma unroll
  for (int ni = 0; ni < 4; ni++) {
    int n = n0 + ni * 16 + fr;
    bias_v[ni] = (n < Nn) ? bias[n] : 0.f;
  }

#pragma unroll
  for (int mi = 0; mi < 4; mi++) {
#pragma unroll
    for (int ni = 0; ni < 4; ni++) {
      int n = n0 + ni * 16 + fr;
      int mbase = m0 + mi * 16 + quad * 4;
      if (MODE == 4) {
        if (n < 384) {
#pragma unroll
          for (int r = 0; r < 4; r++)
            ((u16*)out)[(size_t)(mbase + r) * 384 + n] =
                f2b(acc[mi][ni][r] + bias_v[ni]);
        } else if (n < 708) {
#pragma unroll
          for (int r = 0; r < 4; r++)
            ((float*)out2)[(size_t)(mbase + r) * 324 + (n - 384)] =
                acc[mi][ni][r] + bias_v[ni];
        }
      } else if (MODE == 2) {
        int b = mbase / HWD;
        int hw = mbase - b * HWD;
        float rv[4];
        if (dtf) {
          const float* xf = (const float*)res;
          float4 qq = *reinterpret_cast<const float4*>(
              &xf[((size_t)b * CC + n) * HWD + hw]);
          rv[0] = qq.x; rv[1] = qq.y; rv[2] = qq.z; rv[3] = qq.w;
        } else {
          const u16* xh = (const u16*)res;
          uint2 qq = *reinterpret_cast<const uint2*>(
              &xh[((size_t)b * CC + n) * HWD + hw]);
          rv[0] = b2f((u16)(qq.x & 0xFFFFu));
          rv[1] = b2f((u16)(qq.x >> 16));
          rv[2] = b2f((u16)(qq.y & 0xFFFFu));
          rv[3] = b2f((u16)(qq.y >> 16));
        }
#pragma unroll
        for (int r = 0; r < 4; r++)
          ((u16*)out)[(size_t)(mbase + r) * 384 + n] =
              f2b(acc[mi][ni][r] + bias_v[ni] + rv[r]);
      } else if (MODE == 3) {
        const u16* rf = (const u16*)res;
        int mg = mbase + moff;
        int b = mg / HWD;
        int hw = mg - b * HWD;
        float vv[4];
#pragma unroll
        for (int r = 0; r < 4; r++)
          vv[r] = acc[mi][ni][r] + bias_v[ni] + b2f(rf[(size_t)(mg + r) * 384 + n]);
        if (dtf) {
          float4 st = make_float4(vv[0], vv[1], vv[2], vv[3]);
          *reinterpret_cast<float4*>(
              &((float*)out)[((size_t)b * CC + n) * HWD + hw]) = st;
        } else {
          uint2 st;
          st.x = (u32)f2b(vv[0]) | ((u32)f2b(vv[1]) << 16);
          st.y = (u32)f2b(vv[2]) | ((u32)f2b(vv[3]) << 16);
          *reinterpret_cast<uint2*>(
              &((u16*)out)[((size_t)b * CC + n) * HWD + hw]) = st;
        }
      } else {  // MODE 0
#pragma unroll
        for (int r = 0; r < 4; r++) {
          float vv = acc[mi][ni][r] + bias_v[ni];
          if (GELU) vv = 0.5f * vv * (1.0f + erff(vv * 0.70710678118654752f));
          if (n < Nn)
            ((u16*)out)[(size_t)(mbase + r) * Nn + n] = f2b(vv);
        }
      }
    }
  }
}

// =====================================================================
extern "C" void kernel_launch(void* const* d_in, const int* in_sizes, int n_in,
                              void* d_out, int out_size, void* d_ws,
                              size_t ws_size, hipStream_t stream) {
  const void* x = d_in[0];
  const void* ln1_g = d_in[1];
  const void* ln1_b = d_in[2];
  const void* vproj_w = d_in[3];
  const void* vproj_b = d_in[4];
  const void* om_w = d_in[5];
  const void* om_b = d_in[6];
  const void* oproj_w = d_in[7];
  const void* oproj_b = d_in[8];
  const void* ln2_g = d_in[9];
  const void* ln2_b = d_in[10];
  const void* fc1_w = d_in[11];
  const void* fc1_b = d_in[12];
  const void* fc2_w = d_in[13];
  const void* fc2_b = d_in[14];

  char* ws = (char*)d_ws;
  const size_t SZ_NC2 = (size_t)NT * CC * 2;         // 9,633,792
  const size_t SZ_OM4 = (size_t)NT * 324 * 4;        // 16,257,024
  // R0: tn -> dcn -> y2            [0, NC2)
  // R1: val -> h (h spans R1+R2)   [NC2, 2*NC2)
  // R2: om f32                     [2*NC2, 2*NC2+OM4)
  // R3: xp1 bf16
  // R4: weights bf16 (3,197,952 B): vprojT|omT (fused 708xK)|oprojT|fc1T|fc2T
  // R5: flag + canonical f32 params
  u16* tn = (u16*)(ws);
  u16* dcn = tn;
  u16* y2 = tn;
  u16* val = (u16*)(ws + SZ_NC2);
  u16* h = val;
  float* om = (float*)(ws + 2 * SZ_NC2);
  u16* xp1 = (u16*)(ws + 2 * SZ_NC2 + SZ_OM4);
  u16* wT = (u16*)(ws + 3 * SZ_NC2 + SZ_OM4);
  u16* vprojT = wT;                  // also the fused (708,384) B matrix
  u16* oprojT = wT + 147456 + 124416;
  u16* fc1T = oprojT + 147456;
  u16* fc2T = fc1T + 589824;
  char* r5 = ws + 3 * SZ_NC2 + SZ_OM4 + 3197952;
  int* flag = (int*)r5;
  float* pf = (float*)r5 + 16;
  float* ln1_gF = pf + 0;
  float* ln1_bF = pf + 384;
  float* ln2_gF = pf + 768;
  float* ln2_bF = pf + 1152;
  float* vom_bF = pf + 1536;   // fused 708: vproj_b(384) then om_b(324)
  float* oproj_bF = pf + 2304;
  float* fc1_bF = pf + 2688;
  float* fc2_bF = pf + 4224;

  probe_kernel<<<1, 64, 0, stream>>>(ln1_g, flag);

  convert_params<<<dim3(6, 9), 256, 0, stream>>>(
      ln1_g, ln1_b, ln2_g, ln2_b, vproj_b, om_b, oproj_b, fc1_b, fc2_b,
      pf, flag);

  convert_weights<<<dim3(576, 5), 256, 0, stream>>>(
      vproj_w, om_w, oproj_w, fc1_w, fc2_w, wT, flag);

  ln1_kernel<<<BB * 49, 256, 0, stream>>>(x, ln1_gF, ln1_bF, tn, flag);

  // fused vproj+om: Mt=196, Ntiles=12 (768 pad, Nn=708) -> 2352 tiles, 588 blocks
  wgemm_k<4, false><<<588, 256, 0, stream>>>(
      tn, vprojT, vom_bF, nullptr, val, om, 196, 12, 708, 384, 0, flag);

  dcn_kernel<<<(NT * GG) / 16, 256, 0, stream>>>(val, om, dcn);

  // oproj: Mt=196, Ntiles=6 -> 1176 tiles, 294 blocks
  wgemm_k<2, false><<<294, 256, 0, stream>>>(
      dcn, oprojT, oproj_bF, x, xp1, nullptr, 196, 6, 384, 384, 0, flag);

  ln2_kernel<<<NT / 4, 256, 0, stream>>>(xp1, ln2_gF, ln2_bF, y2);

  // fc1 + fc2 in 2 M-chunks of 6272 rows; h overlays R1+R2
  for (int c = 0; c < 2; c++) {
    int r0 = c * 6272;
    // fc1: Mt=98, Ntiles=24 -> 2352 tiles, 588 blocks
    wgemm_k<0, true><<<588, 256, 0, stream>>>(
        y2 + (size_t)r0 * CC, fc1T, fc1_bF, nullptr, h, nullptr,
        98, 24, HID, 384, 0, flag);
    // fc2: Mt=98, Ntiles=6 -> 588 tiles, 147 blocks
    wgemm_k<3, false><<<147, 256, 0, stream>>>(
        h, fc2T, fc2_bF, xp1, d_out, nullptr, 98, 6, 384, HID, r0, flag);
  }
}